// Round 15
// baseline (68.549 us; speedup 1.0000x reference)
//
#include <hip/hip_runtime.h>
#include <math.h>

typedef unsigned short u16;
typedef short bf16x8 __attribute__((ext_vector_type(8)));
typedef float f32x4 __attribute__((ext_vector_type(4)));

#define BN 4
#define SN 512
#define DN 768
#define NHN 12
#define DHN 64
#define EXPN 32
#define INVN 64

#define TAB_T0 -20.5f
#define TAB_DLT (23.5f / 448.0f)
#define TAB_SCALE (448.0f / 23.5f)

__device__ __forceinline__ u16 f2b(float f) {
    union { float f; unsigned int u; } v; v.f = f;
    unsigned int r = v.u + 0x7FFFu + ((v.u >> 16) & 1u);
    return (u16)(r >> 16);
}
__device__ __forceinline__ u16 f2h(float f) {
    union { _Float16 h; u16 u; } v; v.h = (_Float16)f; return v.u;
}

#define GLD16(g, l) __builtin_amdgcn_global_load_lds( \
    (__attribute__((address_space(1))) const void*)(g), \
    (__attribute__((address_space(3))) void*)(l), 16, 0, 0)

// ---------------------------------------------------------------------------
// Kernel 0: f32->bf16 conversion of X/Wq/Wk/Wv, PLUS (blockIdx.y==4) the
// exp-MLP piecewise-linear table: tbl[i]=(y(t_i), y(t_{i+1})-y(t_i)), 450 ent.
// ---------------------------------------------------------------------------
__global__ __launch_bounds__(256) void prep(
    const float* __restrict__ X, const float* __restrict__ Wq,
    const float* __restrict__ Wk, const float* __restrict__ Wv,
    const float* __restrict__ ew1, const float* __restrict__ eb1,
    const float* __restrict__ ew2, const float* __restrict__ eb2,
    u16* __restrict__ Xb, u16* __restrict__ Wqb,
    u16* __restrict__ Wkb, u16* __restrict__ Wvb,
    float2* __restrict__ tbl)
{
    if (blockIdx.y == 4) {
        int i = blockIdx.x * 256 + threadIdx.x;
        if (i > 449) return;
        float t0 = TAB_T0 + i * TAB_DLT;
        float t1 = t0 + TAB_DLT;
        float y0 = eb2[0], y1 = y0;
        #pragma unroll 8
        for (int n = 0; n < EXPN; ++n) {
            float w1 = ew1[n], b1 = eb1[n], w2 = ew2[n];
            y0 += fmaxf(fmaf(t0, w1, b1), 0.f) * w2;
            y1 += fmaxf(fmaf(t1, w1, b1), 0.f) * w2;
        }
        tbl[i] = make_float2(y0, y1 - y0);
        return;
    }
    const float* s; u16* d; int n;
    switch (blockIdx.y) {
        case 0:  s = X;  d = Xb;  n = (BN * SN) * DN; break;
        case 1:  s = Wq; d = Wqb; n = DN * DN; break;
        case 2:  s = Wk; d = Wkb; n = DN * DN; break;
        default: s = Wv; d = Wvb; n = DN * DN; break;
    }
    int i = (blockIdx.x * 256 + threadIdx.x) * 4;
    if (i < n) {
        float4 v = *(const float4*)&s[i];
        unsigned int lo = (unsigned)f2b(v.x) | ((unsigned)f2b(v.y) << 16);
        unsigned int hi = (unsigned)f2b(v.z) | ((unsigned)f2b(v.w) << 16);
        *(uint2*)&d[i] = make_uint2(lo, hi);
    }
}

// ---------------------------------------------------------------------------
// Kernel 1: fused QKV projection (m97-style). BM=128 x BN=64, BK=32, 4 waves,
// global_load_lds staging, XOR-swizzled LDS. Q/K stored bf16 [B,NH,S,DH];
// V stored TRANSPOSED f16 [B,NH,DH,S].
// ---------------------------------------------------------------------------
__global__ __launch_bounds__(256) void qkv_mfma(
    const u16* __restrict__ Xb,
    const u16* __restrict__ Wqb, const u16* __restrict__ Wkb, const u16* __restrict__ Wvb,
    const float* __restrict__ bq, const float* __restrict__ bk, const float* __restrict__ bv,
    u16* __restrict__ Qb, u16* __restrict__ Kb, u16* __restrict__ Vtr)
{
    __shared__ __align__(16) u16 As[128 * 32];
    __shared__ __align__(16) u16 Bs[64 * 32];

    const int tid = threadIdx.x, w = tid >> 6, l = tid & 63;
    const int lr = l & 15, lg = l >> 4;
    const int m0 = blockIdx.y * 128;
    const int nsel = blockIdx.x / 12;
    const int n0l = (blockIdx.x % 12) * 64;
    const u16* W = (nsel == 0) ? Wqb : (nsel == 1) ? Wkb : Wvb;
    const float* bias = (nsel == 0) ? bq : (nsel == 1) ? bk : bv;

    const int wm = w >> 1, wn = w & 1;

    const int oA0 = tid * 16;
    const int rA0 = oA0 >> 6, sA0 = (oA0 >> 4) & 3;
    const int cA0 = (sA0 ^ ((rA0 >> 1) & 3)) * 8;
    const int oA1 = oA0 + 4096;
    const int rA1 = oA1 >> 6, sA1 = (oA1 >> 4) & 3;
    const int cA1 = (sA1 ^ ((rA1 >> 1) & 3)) * 8;
    const u16* gA0 = Xb + (m0 + rA0) * DN + cA0;
    const u16* gA1 = Xb + (m0 + rA1) * DN + cA1;
    const u16* gB  = W + (n0l + rA0) * DN + cA0;

    int offA[4], offB[2];
    #pragma unroll
    for (int mi = 0; mi < 4; ++mi) {
        int row = wm * 64 + mi * 16 + lr;
        offA[mi] = row * 64 + ((lg ^ ((row >> 1) & 3)) * 16);
    }
    #pragma unroll
    for (int ni = 0; ni < 2; ++ni) {
        int row = wn * 32 + ni * 16 + lr;
        offB[ni] = row * 64 + ((lg ^ ((row >> 1) & 3)) * 16);
    }

    f32x4 acc[4][2];
    #pragma unroll
    for (int mi = 0; mi < 4; ++mi)
        #pragma unroll
        for (int ni = 0; ni < 2; ++ni) acc[mi][ni] = (f32x4){0.f, 0.f, 0.f, 0.f};

    for (int k0 = 0; k0 < DN; k0 += 32) {
        __syncthreads();
        GLD16(gA0 + k0, (char*)As + oA0);
        GLD16(gA1 + k0, (char*)As + oA1);
        GLD16(gB  + k0, (char*)Bs + oA0);
        __syncthreads();

        bf16x8 af[4], bff[2];
        #pragma unroll
        for (int mi = 0; mi < 4; ++mi) af[mi] = *(const bf16x8*)((const char*)As + offA[mi]);
        #pragma unroll
        for (int ni = 0; ni < 2; ++ni) bff[ni] = *(const bf16x8*)((const char*)Bs + offB[ni]);
        #pragma unroll
        for (int mi = 0; mi < 4; ++mi)
            #pragma unroll
            for (int ni = 0; ni < 2; ++ni)
                acc[mi][ni] = __builtin_amdgcn_mfma_f32_16x16x32_bf16(af[mi], bff[ni], acc[mi][ni], 0, 0, 0);
    }

    if (nsel < 2) {
        u16* out = (nsel == 0) ? Qb : Kb;
        #pragma unroll
        for (int ni = 0; ni < 2; ++ni) {
            int col = n0l + wn * 32 + ni * 16 + lr;
            float bc = bias[col];
            int hh = col >> 6, dh = col & 63;
            #pragma unroll
            for (int mi = 0; mi < 4; ++mi) {
                #pragma unroll
                for (int r = 0; r < 4; ++r) {
                    int m = m0 + wm * 64 + mi * 16 + lg * 4 + r;
                    int bi = m >> 9, srow = m & 511;
                    out[(((bi * NHN + hh) * SN) + srow) * DHN + dh] = f2b(acc[mi][ni][r] + bc);
                }
            }
        }
    } else {
        #pragma unroll
        for (int ni = 0; ni < 2; ++ni) {
            int col = n0l + wn * 32 + ni * 16 + lr;
            float bc = bias[col];
            int hh = col >> 6, dh = col & 63;
            #pragma unroll
            for (int mi = 0; mi < 4; ++mi) {
                int m = m0 + wm * 64 + mi * 16 + lg * 4;
                int bi = m >> 9, srow = m & 511;
                ushort4 pk;
                pk.x = f2h(acc[mi][ni][0] + bc);
                pk.y = f2h(acc[mi][ni][1] + bc);
                pk.z = f2h(acc[mi][ni][2] + bc);
                pk.w = f2h(acc[mi][ni][3] + bc);
                *(ushort4*)&Vtr[((size_t)(bi * NHN + hh) * DHN + dh) * SN + srow] = pk;
            }
        }
    }
}

// ---------------------------------------------------------------------------
// Kernel 2: attention — R13 structure (kh-split PV, V read once, setprio)
// with pvbuf ALIASED into sb (dead after PV reads; one extra barrier).
// LDS ~40.4 KB -> 4 blocks/CU = 32 waves/CU.
// ---------------------------------------------------------------------------
__global__ __launch_bounds__(512, 8) void attn_mfma(
    const u16* __restrict__ Qb, const u16* __restrict__ Kb, const u16* __restrict__ Vtr,
    const float* __restrict__ mask, const float2* __restrict__ tbl,
    const float* __restrict__ iw1, const float* __restrict__ ib1,
    const float* __restrict__ iw2, const float* __restrict__ ib2,
    float* __restrict__ out)
{
    __shared__ __align__(16) u16 sb[32 * 512];     // X_up tile; pvbuf aliases head
    __shared__ __align__(16) float2 tab[450];      // PWL table (3.6 KB)
    __shared__ float ms[SN];
    __shared__ float wI1[INVN], wIb1[INVN], wI2[INVN];
    __shared__ float partw[8][32];
    __shared__ float scale_s[32];
    __shared__ float scal;

    const int tid = threadIdx.x, w = tid >> 6, l = tid & 63;
    const int lr = l & 15, lg = l >> 4, kb8 = lg * 8;
    const int bid = blockIdx.x;
    const int bh = bid >> 4;                       // head 0..47
    const int q0 = (bid & 15) * 32;
    const int b = bh / NHN, h = bh % NHN;
    const u16* Qh = Qb + (size_t)bh * SN * DHN;
    const u16* Kh = Kb + (size_t)bh * SN * DHN;
    const u16* VTh = Vtr + (size_t)bh * DHN * SN;

    if (tid < INVN) { wI1[tid] = iw1[tid]; wIb1[tid] = ib1[tid]; wI2[tid] = iw2[tid]; }
    if (tid == 511) scal = ib2[0];
    if (tid < SN) ms[tid] = mask[b * SN + tid];
    if (tid < 450) tab[tid] = tbl[tid];
    __syncthreads();

    const float ib2v = scal;

    // Q A-fragments for both m-tiles (rows q0..q0+31)
    bf16x8 aq00 = *(const bf16x8*)(Qh + (q0 + lr) * DHN + kb8);
    bf16x8 aq01 = *(const bf16x8*)(Qh + (q0 + lr) * DHN + 32 + kb8);
    bf16x8 aq10 = *(const bf16x8*)(Qh + (q0 + 16 + lr) * DHN + kb8);
    bf16x8 aq11 = *(const bf16x8*)(Qh + (q0 + 16 + lr) * DHN + 32 + kb8);

    // refs: score[b,h,0,q0+row] via Q0-replicated A, per m-tile
    float myref0[4], myref1[4];
    {
        bf16x8 a00 = *(const bf16x8*)(Qh + kb8);
        bf16x8 a01 = *(const bf16x8*)(Qh + 32 + kb8);
        const u16* kp0 = Kh + (q0 + lr) * DHN + kb8;
        bf16x8 b00 = *(const bf16x8*)(kp0);
        bf16x8 b01 = *(const bf16x8*)(kp0 + 32);
        const u16* kp1 = Kh + (q0 + 16 + lr) * DHN + kb8;
        bf16x8 b10 = *(const bf16x8*)(kp1);
        bf16x8 b11 = *(const bf16x8*)(kp1 + 32);
        f32x4 d0 = {0.f, 0.f, 0.f, 0.f}, d1 = {0.f, 0.f, 0.f, 0.f};
        d0 = __builtin_amdgcn_mfma_f32_16x16x32_bf16(a00, b00, d0, 0, 0, 0);
        d0 = __builtin_amdgcn_mfma_f32_16x16x32_bf16(a01, b01, d0, 0, 0, 0);
        d1 = __builtin_amdgcn_mfma_f32_16x16x32_bf16(a00, b10, d1, 0, 0, 0);
        d1 = __builtin_amdgcn_mfma_f32_16x16x32_bf16(a01, b11, d1, 0, 0, 0);
        float rc0 = d0[0] * 0.125f + ms[q0 + lr];
        float rc1 = d1[0] * 0.125f + ms[q0 + 16 + lr];
        #pragma unroll
        for (int r = 0; r < 4; ++r) {
            myref0[r] = __shfl(rc0, lg * 4 + r);
            myref1[r] = __shfl(rc1, lg * 4 + r);
        }
    }

    // ---- fused QK^T + table lookup over this wave's 64-key strip ----
    char* sbb = (char*)sb;
    float part0[4] = {0.f, 0.f, 0.f, 0.f};
    float part1[4] = {0.f, 0.f, 0.f, 0.f};
    const u16* kpp = Kh + (w * 64 + lr) * DHN + kb8;
    bf16x8 nb0 = *(const bf16x8*)(kpp);
    bf16x8 nb1 = *(const bf16x8*)(kpp + 32);
    #pragma unroll
    for (int i = 0; i < 4; ++i) {
        bf16x8 b0 = nb0, b1 = nb1;
        if (i < 3) {
            const u16* kn = kpp + (i + 1) * 16 * DHN;
            nb0 = *(const bf16x8*)(kn);
            nb1 = *(const bf16x8*)(kn + 32);
        }
        f32x4 d0 = {0.f, 0.f, 0.f, 0.f}, d1 = {0.f, 0.f, 0.f, 0.f};
        __builtin_amdgcn_s_setprio(1);
        d0 = __builtin_amdgcn_mfma_f32_16x16x32_bf16(aq00, b0, d0, 0, 0, 0);
        d0 = __builtin_amdgcn_mfma_f32_16x16x32_bf16(aq01, b1, d0, 0, 0, 0);
        d1 = __builtin_amdgcn_mfma_f32_16x16x32_bf16(aq10, b0, d1, 0, 0, 0);
        d1 = __builtin_amdgcn_mfma_f32_16x16x32_bf16(aq11, b1, d1, 0, 0, 0);
        __builtin_amdgcn_s_setprio(0);
        const int col0 = w * 64 + i * 16;
        const float mv = ms[col0 + lr];
        const int colb = (col0 + lr) * 2;
        #pragma unroll
        for (int r = 0; r < 4; ++r) {
            {   // m-tile 0, row = lg*4+r
                float tp = fminf(d0[r] * 0.125f + mv - (myref0[r] - 1.0f), 3.0f);
                float v = (tp - TAB_T0) * TAB_SCALE;
                int idx = (int)v;
                idx = idx < 0 ? 0 : idx;
                float fr = v - (float)idx;
                float2 p = tab[idx];
                float e = fmaf(fr, p.y, p.x);
                float xu = (tp > -20.0f) ? e : 0.f;
                part0[r] += xu;
                int row = lg * 4 + r;
                *(u16*)(sbb + row * 1024 + (colb ^ ((row & 7) << 4))) = f2h(xu);
            }
            {   // m-tile 1, row = 16 + lg*4+r
                float tp = fminf(d1[r] * 0.125f + mv - (myref1[r] - 1.0f), 3.0f);
                float v = (tp - TAB_T0) * TAB_SCALE;
                int idx = (int)v;
                idx = idx < 0 ? 0 : idx;
                float fr = v - (float)idx;
                float2 p = tab[idx];
                float e = fmaf(fr, p.y, p.x);
                float xu = (tp > -20.0f) ? e : 0.f;
                part1[r] += xu;
                int row = 16 + lg * 4 + r;
                *(u16*)(sbb + row * 1024 + (colb ^ ((row & 7) << 4))) = f2h(xu);
            }
        }
    }
    // partition partials: reduce across the 16 lanes of each lg group
    #pragma unroll
    for (int r = 0; r < 4; ++r) {
        #pragma unroll
        for (int s = 1; s < 16; s <<= 1) {
            part0[r] += __shfl_xor(part0[r], s);
            part1[r] += __shfl_xor(part1[r], s);
        }
    }
    if (lr == 0) {
        #pragma unroll
        for (int r = 0; r < 4; ++r) {
            partw[w][lg * 4 + r] = part0[r];
            partw[w][16 + lg * 4 + r] = part1[r];
        }
    }
    __syncthreads();

    // ---- row scales: wave w handles rows 4w..4w+3 (inv MLP lane-parallel) ----
    #pragma unroll
    for (int rr = 0; rr < 4; ++rr) {
        const int row = w * 4 + rr;
        float pt = 0.f;
        #pragma unroll
        for (int ww = 0; ww < 8; ++ww) pt += partw[ww][row];
        float hu = fmaxf(fmaf(pt, wI1[l], wIb1[l]), 0.f) * wI2[l];
        #pragma unroll
        for (int s = 32; s > 0; s >>= 1) hu += __shfl_xor(hu, s);
        const float pinv = hu + ib2v;
        const float p2 = pt * pinv;                 // == sum(X_up*pinv) exactly
        float hu2 = fmaxf(fmaf(p2, wI1[l], wIb1[l]), 0.f) * wI2[l];
        #pragma unroll
        for (int s = 32; s > 0; s >>= 1) hu2 += __shfl_xor(hu2, s);
        const float pinv2 = hu2 + ib2v;
        if (l == 0) scale_s[row] = pinv * ((p2 > 1.5f) ? pinv2 : 1.0f);
    }

    // ---- PV (f16 MFMA): dh strip ds=(w&3)*16, K-half kh=w>>2, both m-tiles,
    //      V read once per block (R13's proven shape) ----
    const int ds = (w & 3) * 16, kh = w >> 2;
    f32x4 acc0 = {0.f, 0.f, 0.f, 0.f}, acc1 = {0.f, 0.f, 0.f, 0.f};
    const u16* vp = VTh + (ds + lr) * SN + kh * 256 + kb8;
    const int swzl = (lr & 7) << 4;
    bf16x8 nv = *(const bf16x8*)(vp);
    #pragma unroll
    for (int k0 = 0; k0 < 256; k0 += 32) {
        bf16x8 bv = nv;
        if (k0 < 224) nv = *(const bf16x8*)(vp + k0 + 32);
        const int kk2 = (kh * 256 + k0 + kb8) * 2;
        bf16x8 a0 = *(const bf16x8*)(sbb + lr * 1024 + (kk2 ^ swzl));
        bf16x8 a1 = *(const bf16x8*)(sbb + (16 + lr) * 1024 + (kk2 ^ swzl));
        __builtin_amdgcn_s_setprio(1);
        acc0 = __builtin_amdgcn_mfma_f32_16x16x32_f16(a0, bv, acc0, 0, 0, 0);
        acc1 = __builtin_amdgcn_mfma_f32_16x16x32_f16(a1, bv, acc1, 0, 0, 0);
        __builtin_amdgcn_s_setprio(0);
    }
    // sb (X_up) is now dead in ALL waves; reuse its head as pvbuf.
    float (*pvbuf)[68] = (float (*)[68])sbb;
    __syncthreads();   // all sb reads complete before aliased writes
    if (kh == 1) {
        #pragma unroll
        for (int r = 0; r < 4; ++r) {
            pvbuf[lg * 4 + r][ds + lr] = acc0[r];
            pvbuf[16 + lg * 4 + r][ds + lr] = acc1[r];
        }
    }
    __syncthreads();
    if (kh == 0) {
        #pragma unroll
        for (int r = 0; r < 4; ++r) {
            const int row0 = lg * 4 + r;
            const int row1 = row0 + 16;
            float v0 = (acc0[r] + pvbuf[row0][ds + lr]) * scale_s[row0];
            float v1 = (acc1[r] + pvbuf[row1][ds + lr]) * scale_s[row1];
            out[(size_t)(b * SN + q0 + row0) * DN + h * DHN + ds + lr] = v0;
            out[(size_t)(b * SN + q0 + row1) * DN + h * DHN + ds + lr] = v1;
        }
    }
}

// ---------------------------------------------------------------------------
extern "C" void kernel_launch(void* const* d_in, const int* in_sizes, int n_in,
                              void* d_out, int out_size, void* d_ws, size_t ws_size,
                              hipStream_t stream) {
    const float* X    = (const float*)d_in[0];
    const float* mask = (const float*)d_in[1];
    const float* Wq   = (const float*)d_in[2];
    const float* bq   = (const float*)d_in[3];
    const float* Wk   = (const float*)d_in[4];
    const float* bk   = (const float*)d_in[5];
    const float* Wv   = (const float*)d_in[6];
    const float* bv   = (const float*)d_in[7];
    const float* ew1  = (const float*)d_in[8];
    const float* eb1  = (const float*)d_in[9];
    const float* ew2  = (const float*)d_in[10];
    const float* eb2  = (const float*)d_in[11];
    const float* iw1  = (const float*)d_in[12];
    const float* ib1  = (const float*)d_in[13];
    const float* iw2  = (const float*)d_in[14];
    const float* ib2  = (const float*)d_in[15];
    float* out = (float*)d_out;

    // workspace layout: table first (8B aligned), then u16 arrays
    float2* tbl = (float2*)d_ws;
    u16* Xb  = (u16*)((char*)d_ws + 4608);
    u16* Wqb = Xb + (size_t)(BN * SN) * DN;
    u16* Wkb = Wqb + DN * DN;
    u16* Wvb = Wkb + DN * DN;
    u16* Qb  = Wvb + DN * DN;
    const size_t per = (size_t)BN * NHN * SN * DHN;
    u16* Kb2 = Qb + per;
    u16* Vb2 = Kb2 + per;              // V^T [B,NH,DH,S], f16

    dim3 gc(1536, 5);                  // y<4: cvt, y==4: table
    prep<<<gc, 256, 0, stream>>>(X, Wq, Wk, Wv, ew1, eb1, ew2, eb2,
                                 Xb, Wqb, Wkb, Wvb, tbl);

    dim3 g1(36, 16);
    qkv_mfma<<<g1, 256, 0, stream>>>(Xb, Wqb, Wkb, Wvb, bq, bk, bv, Qb, Kb2, Vb2);

    attn_mfma<<<dim3(768), 512, 0, stream>>>(Qb, Kb2, Vb2, mask, tbl,
                                             iw1, ib1, iw2, ib2, out);
}

// Round 16
// 55.784 us; speedup vs baseline: 1.2288x; 1.2288x over previous
//
#include <hip/hip_runtime.h>
#include <math.h>

typedef unsigned short u16;
typedef short bf16x8 __attribute__((ext_vector_type(8)));
typedef float f32x4 __attribute__((ext_vector_type(4)));

#define BN 4
#define SN 512
#define DN 768
#define NHN 12
#define DHN 64
#define EXPN 32
#define INVN 64

#define TAB_T0 -20.5f
#define TAB_DLT (23.5f / 448.0f)
#define TAB_SCALE (448.0f / 23.5f)

__device__ __forceinline__ u16 f2b(float f) {
    union { float f; unsigned int u; } v; v.f = f;
    unsigned int r = v.u + 0x7FFFu + ((v.u >> 16) & 1u);
    return (u16)(r >> 16);
}
__device__ __forceinline__ u16 f2h(float f) {
    union { _Float16 h; u16 u; } v; v.h = (_Float16)f; return v.u;
}

#define GLD16(g, l) __builtin_amdgcn_global_load_lds( \
    (__attribute__((address_space(1))) const void*)(g), \
    (__attribute__((address_space(3))) void*)(l), 16, 0, 0)

// ---------------------------------------------------------------------------
// Kernel 0: f32->bf16 conversion of X/Wq/Wk/Wv, PLUS (blockIdx.y==4) the
// exp-MLP piecewise-linear table: tbl[i]=(y(t_i), y(t_{i+1})-y(t_i)), 450 ent.
// ---------------------------------------------------------------------------
__global__ __launch_bounds__(256) void prep(
    const float* __restrict__ X, const float* __restrict__ Wq,
    const float* __restrict__ Wk, const float* __restrict__ Wv,
    const float* __restrict__ ew1, const float* __restrict__ eb1,
    const float* __restrict__ ew2, const float* __restrict__ eb2,
    u16* __restrict__ Xb, u16* __restrict__ Wqb,
    u16* __restrict__ Wkb, u16* __restrict__ Wvb,
    float2* __restrict__ tbl)
{
    if (blockIdx.y == 4) {
        int i = blockIdx.x * 256 + threadIdx.x;
        if (i > 449) return;
        float t0 = TAB_T0 + i * TAB_DLT;
        float t1 = t0 + TAB_DLT;
        float y0 = eb2[0], y1 = y0;
        #pragma unroll 8
        for (int n = 0; n < EXPN; ++n) {
            float w1 = ew1[n], b1 = eb1[n], w2 = ew2[n];
            y0 += fmaxf(fmaf(t0, w1, b1), 0.f) * w2;
            y1 += fmaxf(fmaf(t1, w1, b1), 0.f) * w2;
        }
        tbl[i] = make_float2(y0, y1 - y0);
        return;
    }
    const float* s; u16* d; int n;
    switch (blockIdx.y) {
        case 0:  s = X;  d = Xb;  n = (BN * SN) * DN; break;
        case 1:  s = Wq; d = Wqb; n = DN * DN; break;
        case 2:  s = Wk; d = Wkb; n = DN * DN; break;
        default: s = Wv; d = Wvb; n = DN * DN; break;
    }
    int i = (blockIdx.x * 256 + threadIdx.x) * 4;
    if (i < n) {
        float4 v = *(const float4*)&s[i];
        unsigned int lo = (unsigned)f2b(v.x) | ((unsigned)f2b(v.y) << 16);
        unsigned int hi = (unsigned)f2b(v.z) | ((unsigned)f2b(v.w) << 16);
        *(uint2*)&d[i] = make_uint2(lo, hi);
    }
}

// ---------------------------------------------------------------------------
// Kernel 1: fused QKV projection (m97-style). BM=128 x BN=64, BK=32, 4 waves,
// global_load_lds staging, XOR-swizzled LDS. Q/K stored bf16 [B,NH,S,DH];
// V stored TRANSPOSED f16 [B,NH,DH,S].
// ---------------------------------------------------------------------------
__global__ __launch_bounds__(256) void qkv_mfma(
    const u16* __restrict__ Xb,
    const u16* __restrict__ Wqb, const u16* __restrict__ Wkb, const u16* __restrict__ Wvb,
    const float* __restrict__ bq, const float* __restrict__ bk, const float* __restrict__ bv,
    u16* __restrict__ Qb, u16* __restrict__ Kb, u16* __restrict__ Vtr)
{
    __shared__ __align__(16) u16 As[128 * 32];
    __shared__ __align__(16) u16 Bs[64 * 32];

    const int tid = threadIdx.x, w = tid >> 6, l = tid & 63;
    const int lr = l & 15, lg = l >> 4;
    const int m0 = blockIdx.y * 128;
    const int nsel = blockIdx.x / 12;
    const int n0l = (blockIdx.x % 12) * 64;
    const u16* W = (nsel == 0) ? Wqb : (nsel == 1) ? Wkb : Wvb;
    const float* bias = (nsel == 0) ? bq : (nsel == 1) ? bk : bv;

    const int wm = w >> 1, wn = w & 1;

    const int oA0 = tid * 16;
    const int rA0 = oA0 >> 6, sA0 = (oA0 >> 4) & 3;
    const int cA0 = (sA0 ^ ((rA0 >> 1) & 3)) * 8;
    const int oA1 = oA0 + 4096;
    const int rA1 = oA1 >> 6, sA1 = (oA1 >> 4) & 3;
    const int cA1 = (sA1 ^ ((rA1 >> 1) & 3)) * 8;
    const u16* gA0 = Xb + (m0 + rA0) * DN + cA0;
    const u16* gA1 = Xb + (m0 + rA1) * DN + cA1;
    const u16* gB  = W + (n0l + rA0) * DN + cA0;

    int offA[4], offB[2];
    #pragma unroll
    for (int mi = 0; mi < 4; ++mi) {
        int row = wm * 64 + mi * 16 + lr;
        offA[mi] = row * 64 + ((lg ^ ((row >> 1) & 3)) * 16);
    }
    #pragma unroll
    for (int ni = 0; ni < 2; ++ni) {
        int row = wn * 32 + ni * 16 + lr;
        offB[ni] = row * 64 + ((lg ^ ((row >> 1) & 3)) * 16);
    }

    f32x4 acc[4][2];
    #pragma unroll
    for (int mi = 0; mi < 4; ++mi)
        #pragma unroll
        for (int ni = 0; ni < 2; ++ni) acc[mi][ni] = (f32x4){0.f, 0.f, 0.f, 0.f};

    for (int k0 = 0; k0 < DN; k0 += 32) {
        __syncthreads();
        GLD16(gA0 + k0, (char*)As + oA0);
        GLD16(gA1 + k0, (char*)As + oA1);
        GLD16(gB  + k0, (char*)Bs + oA0);
        __syncthreads();

        bf16x8 af[4], bff[2];
        #pragma unroll
        for (int mi = 0; mi < 4; ++mi) af[mi] = *(const bf16x8*)((const char*)As + offA[mi]);
        #pragma unroll
        for (int ni = 0; ni < 2; ++ni) bff[ni] = *(const bf16x8*)((const char*)Bs + offB[ni]);
        #pragma unroll
        for (int mi = 0; mi < 4; ++mi)
            #pragma unroll
            for (int ni = 0; ni < 2; ++ni)
                acc[mi][ni] = __builtin_amdgcn_mfma_f32_16x16x32_bf16(af[mi], bff[ni], acc[mi][ni], 0, 0, 0);
    }

    if (nsel < 2) {
        u16* out = (nsel == 0) ? Qb : Kb;
        #pragma unroll
        for (int ni = 0; ni < 2; ++ni) {
            int col = n0l + wn * 32 + ni * 16 + lr;
            float bc = bias[col];
            int hh = col >> 6, dh = col & 63;
            #pragma unroll
            for (int mi = 0; mi < 4; ++mi) {
                #pragma unroll
                for (int r = 0; r < 4; ++r) {
                    int m = m0 + wm * 64 + mi * 16 + lg * 4 + r;
                    int bi = m >> 9, srow = m & 511;
                    out[(((bi * NHN + hh) * SN) + srow) * DHN + dh] = f2b(acc[mi][ni][r] + bc);
                }
            }
        }
    } else {
        #pragma unroll
        for (int ni = 0; ni < 2; ++ni) {
            int col = n0l + wn * 32 + ni * 16 + lr;
            float bc = bias[col];
            int hh = col >> 6, dh = col & 63;
            #pragma unroll
            for (int mi = 0; mi < 4; ++mi) {
                int m = m0 + wm * 64 + mi * 16 + lg * 4;
                int bi = m >> 9, srow = m & 511;
                ushort4 pk;
                pk.x = f2h(acc[mi][ni][0] + bc);
                pk.y = f2h(acc[mi][ni][1] + bc);
                pk.z = f2h(acc[mi][ni][2] + bc);
                pk.w = f2h(acc[mi][ni][3] + bc);
                *(ushort4*)&Vtr[((size_t)(bi * NHN + hh) * DHN + dh) * SN + srow] = pk;
            }
        }
    }
}

// ---------------------------------------------------------------------------
// Kernel 2: attention — R13 structure (kh-split PV, V read once, setprio),
// pvbuf aliased into sb, 450-entry table. LDS 40448 B -> 4 blocks/CU;
// __launch_bounds__(512,6) = R13's no-spill register budget (VGPR~40).
// ---------------------------------------------------------------------------
__global__ __launch_bounds__(512, 6) void attn_mfma(
    const u16* __restrict__ Qb, const u16* __restrict__ Kb, const u16* __restrict__ Vtr,
    const float* __restrict__ mask, const float2* __restrict__ tbl,
    const float* __restrict__ iw1, const float* __restrict__ ib1,
    const float* __restrict__ iw2, const float* __restrict__ ib2,
    float* __restrict__ out)
{
    __shared__ __align__(16) u16 sb[32 * 512];     // X_up tile; pvbuf aliases head
    __shared__ __align__(16) float2 tab[450];      // PWL table (3.6 KB)
    __shared__ float ms[SN];
    __shared__ float wI1[INVN], wIb1[INVN], wI2[INVN];
    __shared__ float partw[8][32];
    __shared__ float scale_s[32];
    __shared__ float scal;

    const int tid = threadIdx.x, w = tid >> 6, l = tid & 63;
    const int lr = l & 15, lg = l >> 4, kb8 = lg * 8;
    const int bid = blockIdx.x;
    const int bh = bid >> 4;                       // head 0..47
    const int q0 = (bid & 15) * 32;
    const int b = bh / NHN, h = bh % NHN;
    const u16* Qh = Qb + (size_t)bh * SN * DHN;
    const u16* Kh = Kb + (size_t)bh * SN * DHN;
    const u16* VTh = Vtr + (size_t)bh * DHN * SN;

    if (tid < INVN) { wI1[tid] = iw1[tid]; wIb1[tid] = ib1[tid]; wI2[tid] = iw2[tid]; }
    if (tid == 511) scal = ib2[0];
    if (tid < SN) ms[tid] = mask[b * SN + tid];
    if (tid < 450) tab[tid] = tbl[tid];
    __syncthreads();

    const float ib2v = scal;

    // Q A-fragments for both m-tiles (rows q0..q0+31)
    bf16x8 aq00 = *(const bf16x8*)(Qh + (q0 + lr) * DHN + kb8);
    bf16x8 aq01 = *(const bf16x8*)(Qh + (q0 + lr) * DHN + 32 + kb8);
    bf16x8 aq10 = *(const bf16x8*)(Qh + (q0 + 16 + lr) * DHN + kb8);
    bf16x8 aq11 = *(const bf16x8*)(Qh + (q0 + 16 + lr) * DHN + 32 + kb8);

    // refs: score[b,h,0,q0+row] via Q0-replicated A, per m-tile
    float myref0[4], myref1[4];
    {
        bf16x8 a00 = *(const bf16x8*)(Qh + kb8);
        bf16x8 a01 = *(const bf16x8*)(Qh + 32 + kb8);
        const u16* kp0 = Kh + (q0 + lr) * DHN + kb8;
        bf16x8 b00 = *(const bf16x8*)(kp0);
        bf16x8 b01 = *(const bf16x8*)(kp0 + 32);
        const u16* kp1 = Kh + (q0 + 16 + lr) * DHN + kb8;
        bf16x8 b10 = *(const bf16x8*)(kp1);
        bf16x8 b11 = *(const bf16x8*)(kp1 + 32);
        f32x4 d0 = {0.f, 0.f, 0.f, 0.f}, d1 = {0.f, 0.f, 0.f, 0.f};
        d0 = __builtin_amdgcn_mfma_f32_16x16x32_bf16(a00, b00, d0, 0, 0, 0);
        d0 = __builtin_amdgcn_mfma_f32_16x16x32_bf16(a01, b01, d0, 0, 0, 0);
        d1 = __builtin_amdgcn_mfma_f32_16x16x32_bf16(a00, b10, d1, 0, 0, 0);
        d1 = __builtin_amdgcn_mfma_f32_16x16x32_bf16(a01, b11, d1, 0, 0, 0);
        float rc0 = d0[0] * 0.125f + ms[q0 + lr];
        float rc1 = d1[0] * 0.125f + ms[q0 + 16 + lr];
        #pragma unroll
        for (int r = 0; r < 4; ++r) {
            myref0[r] = __shfl(rc0, lg * 4 + r);
            myref1[r] = __shfl(rc1, lg * 4 + r);
        }
    }

    // ---- fused QK^T + table lookup over this wave's 64-key strip ----
    char* sbb = (char*)sb;
    float part0[4] = {0.f, 0.f, 0.f, 0.f};
    float part1[4] = {0.f, 0.f, 0.f, 0.f};
    const u16* kpp = Kh + (w * 64 + lr) * DHN + kb8;
    bf16x8 nb0 = *(const bf16x8*)(kpp);
    bf16x8 nb1 = *(const bf16x8*)(kpp + 32);
    #pragma unroll
    for (int i = 0; i < 4; ++i) {
        bf16x8 b0 = nb0, b1 = nb1;
        if (i < 3) {
            const u16* kn = kpp + (i + 1) * 16 * DHN;
            nb0 = *(const bf16x8*)(kn);
            nb1 = *(const bf16x8*)(kn + 32);
        }
        f32x4 d0 = {0.f, 0.f, 0.f, 0.f}, d1 = {0.f, 0.f, 0.f, 0.f};
        __builtin_amdgcn_s_setprio(1);
        d0 = __builtin_amdgcn_mfma_f32_16x16x32_bf16(aq00, b0, d0, 0, 0, 0);
        d0 = __builtin_amdgcn_mfma_f32_16x16x32_bf16(aq01, b1, d0, 0, 0, 0);
        d1 = __builtin_amdgcn_mfma_f32_16x16x32_bf16(aq10, b0, d1, 0, 0, 0);
        d1 = __builtin_amdgcn_mfma_f32_16x16x32_bf16(aq11, b1, d1, 0, 0, 0);
        __builtin_amdgcn_s_setprio(0);
        const int col0 = w * 64 + i * 16;
        const float mv = ms[col0 + lr];
        const int colb = (col0 + lr) * 2;
        #pragma unroll
        for (int r = 0; r < 4; ++r) {
            {   // m-tile 0, row = lg*4+r
                float tp = fminf(d0[r] * 0.125f + mv - (myref0[r] - 1.0f), 3.0f);
                float v = (tp - TAB_T0) * TAB_SCALE;
                int idx = (int)v;
                idx = idx < 0 ? 0 : idx;
                float fr = v - (float)idx;
                float2 p = tab[idx];
                float e = fmaf(fr, p.y, p.x);
                float xu = (tp > -20.0f) ? e : 0.f;
                part0[r] += xu;
                int row = lg * 4 + r;
                *(u16*)(sbb + row * 1024 + (colb ^ ((row & 7) << 4))) = f2h(xu);
            }
            {   // m-tile 1, row = 16 + lg*4+r
                float tp = fminf(d1[r] * 0.125f + mv - (myref1[r] - 1.0f), 3.0f);
                float v = (tp - TAB_T0) * TAB_SCALE;
                int idx = (int)v;
                idx = idx < 0 ? 0 : idx;
                float fr = v - (float)idx;
                float2 p = tab[idx];
                float e = fmaf(fr, p.y, p.x);
                float xu = (tp > -20.0f) ? e : 0.f;
                part1[r] += xu;
                int row = 16 + lg * 4 + r;
                *(u16*)(sbb + row * 1024 + (colb ^ ((row & 7) << 4))) = f2h(xu);
            }
        }
    }
    // partition partials: reduce across the 16 lanes of each lg group
    #pragma unroll
    for (int r = 0; r < 4; ++r) {
        #pragma unroll
        for (int s = 1; s < 16; s <<= 1) {
            part0[r] += __shfl_xor(part0[r], s);
            part1[r] += __shfl_xor(part1[r], s);
        }
    }
    if (lr == 0) {
        #pragma unroll
        for (int r = 0; r < 4; ++r) {
            partw[w][lg * 4 + r] = part0[r];
            partw[w][16 + lg * 4 + r] = part1[r];
        }
    }
    __syncthreads();

    // ---- row scales: wave w handles rows 4w..4w+3 (inv MLP lane-parallel) ----
    #pragma unroll
    for (int rr = 0; rr < 4; ++rr) {
        const int row = w * 4 + rr;
        float pt = 0.f;
        #pragma unroll
        for (int ww = 0; ww < 8; ++ww) pt += partw[ww][row];
        float hu = fmaxf(fmaf(pt, wI1[l], wIb1[l]), 0.f) * wI2[l];
        #pragma unroll
        for (int s = 32; s > 0; s >>= 1) hu += __shfl_xor(hu, s);
        const float pinv = hu + ib2v;
        const float p2 = pt * pinv;                 // == sum(X_up*pinv) exactly
        float hu2 = fmaxf(fmaf(p2, wI1[l], wIb1[l]), 0.f) * wI2[l];
        #pragma unroll
        for (int s = 32; s > 0; s >>= 1) hu2 += __shfl_xor(hu2, s);
        const float pinv2 = hu2 + ib2v;
        if (l == 0) scale_s[row] = pinv * ((p2 > 1.5f) ? pinv2 : 1.0f);
    }

    // ---- PV (f16 MFMA): dh strip ds=(w&3)*16, K-half kh=w>>2, both m-tiles,
    //      V read once per block (R13's proven shape) ----
    const int ds = (w & 3) * 16, kh = w >> 2;
    f32x4 acc0 = {0.f, 0.f, 0.f, 0.f}, acc1 = {0.f, 0.f, 0.f, 0.f};
    const u16* vp = VTh + (ds + lr) * SN + kh * 256 + kb8;
    const int swzl = (lr & 7) << 4;
    bf16x8 nv = *(const bf16x8*)(vp);
    #pragma unroll
    for (int k0 = 0; k0 < 256; k0 += 32) {
        bf16x8 bv = nv;
        if (k0 < 224) nv = *(const bf16x8*)(vp + k0 + 32);
        const int kk2 = (kh * 256 + k0 + kb8) * 2;
        bf16x8 a0 = *(const bf16x8*)(sbb + lr * 1024 + (kk2 ^ swzl));
        bf16x8 a1 = *(const bf16x8*)(sbb + (16 + lr) * 1024 + (kk2 ^ swzl));
        __builtin_amdgcn_s_setprio(1);
        acc0 = __builtin_amdgcn_mfma_f32_16x16x32_f16(a0, bv, acc0, 0, 0, 0);
        acc1 = __builtin_amdgcn_mfma_f32_16x16x32_f16(a1, bv, acc1, 0, 0, 0);
        __builtin_amdgcn_s_setprio(0);
    }
    // sb (X_up) is now dead in ALL waves; reuse its head as pvbuf.
    float (*pvbuf)[68] = (float (*)[68])sbb;
    __syncthreads();   // all sb reads complete before aliased writes
    if (kh == 1) {
        #pragma unroll
        for (int r = 0; r < 4; ++r) {
            pvbuf[lg * 4 + r][ds + lr] = acc0[r];
            pvbuf[16 + lg * 4 + r][ds + lr] = acc1[r];
        }
    }
    __syncthreads();
    if (kh == 0) {
        #pragma unroll
        for (int r = 0; r < 4; ++r) {
            const int row0 = lg * 4 + r;
            const int row1 = row0 + 16;
            float v0 = (acc0[r] + pvbuf[row0][ds + lr]) * scale_s[row0];
            float v1 = (acc1[r] + pvbuf[row1][ds + lr]) * scale_s[row1];
            out[(size_t)(b * SN + q0 + row0) * DN + h * DHN + ds + lr] = v0;
            out[(size_t)(b * SN + q0 + row1) * DN + h * DHN + ds + lr] = v1;
        }
    }
}

// ---------------------------------------------------------------------------
extern "C" void kernel_launch(void* const* d_in, const int* in_sizes, int n_in,
                              void* d_out, int out_size, void* d_ws, size_t ws_size,
                              hipStream_t stream) {
    const float* X    = (const float*)d_in[0];
    const float* mask = (const float*)d_in[1];
    const float* Wq   = (const float*)d_in[2];
    const float* bq   = (const float*)d_in[3];
    const float* Wk   = (const float*)d_in[4];
    const float* bk   = (const float*)d_in[5];
    const float* Wv   = (const float*)d_in[6];
    const float* bv   = (const float*)d_in[7];
    const float* ew1  = (const float*)d_in[8];
    const float* eb1  = (const float*)d_in[9];
    const float* ew2  = (const float*)d_in[10];
    const float* eb2  = (const float*)d_in[11];
    const float* iw1  = (const float*)d_in[12];
    const float* ib1  = (const float*)d_in[13];
    const float* iw2  = (const float*)d_in[14];
    const float* ib2  = (const float*)d_in[15];
    float* out = (float*)d_out;

    // workspace layout: table first (8B aligned), then u16 arrays
    float2* tbl = (float2*)d_ws;
    u16* Xb  = (u16*)((char*)d_ws + 4608);
    u16* Wqb = Xb + (size_t)(BN * SN) * DN;
    u16* Wkb = Wqb + DN * DN;
    u16* Wvb = Wkb + DN * DN;
    u16* Qb  = Wvb + DN * DN;
    const size_t per = (size_t)BN * NHN * SN * DHN;
    u16* Kb2 = Qb + per;
    u16* Vb2 = Kb2 + per;              // V^T [B,NH,DH,S], f16

    dim3 gc(1536, 5);                  // y<4: cvt, y==4: table
    prep<<<gc, 256, 0, stream>>>(X, Wq, Wk, Wv, ew1, eb1, ew2, eb2,
                                 Xb, Wqb, Wkb, Wvb, tbl);

    dim3 g1(36, 16);
    qkv_mfma<<<g1, 256, 0, stream>>>(Xb, Wqb, Wkb, Wvb, bq, bk, bv, Qb, Kb2, Vb2);

    attn_mfma<<<dim3(768), 512, 0, stream>>>(Qb, Kb2, Vb2, mask, tbl,
                                             iw1, ib1, iw2, ib2, out);
}

// Round 17
// 52.624 us; speedup vs baseline: 1.3026x; 1.0601x over previous
//
#include <hip/hip_runtime.h>
#include <math.h>

typedef unsigned short u16;
typedef short bf16x8 __attribute__((ext_vector_type(8)));
typedef float f32x4 __attribute__((ext_vector_type(4)));

#define BN 4
#define SN 512
#define DN 768
#define NHN 12
#define DHN 64
#define EXPN 32
#define INVN 64

#define TAB_T0 -20.5f
#define TAB_DLT (23.5f / 448.0f)
#define TAB_SCALE (448.0f / 23.5f)

__device__ __forceinline__ u16 f2b(float f) {
    union { float f; unsigned int u; } v; v.f = f;
    unsigned int r = v.u + 0x7FFFu + ((v.u >> 16) & 1u);
    return (u16)(r >> 16);
}
__device__ __forceinline__ u16 f2h(float f) {
    union { _Float16 h; u16 u; } v; v.h = (_Float16)f; return v.u;
}

#define GLD16(g, l) __builtin_amdgcn_global_load_lds( \
    (__attribute__((address_space(1))) const void*)(g), \
    (__attribute__((address_space(3))) void*)(l), 16, 0, 0)

// ---------------------------------------------------------------------------
// Kernel 0: f32->bf16 conversion of X/Wq/Wk/Wv, PLUS (blockIdx.y==4) the
// exp-MLP piecewise-linear table: tbl[i]=(y(t_i), y(t_{i+1})-y(t_i)), 450 ent.
// ---------------------------------------------------------------------------
__global__ __launch_bounds__(256) void prep(
    const float* __restrict__ X, const float* __restrict__ Wq,
    const float* __restrict__ Wk, const float* __restrict__ Wv,
    const float* __restrict__ ew1, const float* __restrict__ eb1,
    const float* __restrict__ ew2, const float* __restrict__ eb2,
    u16* __restrict__ Xb, u16* __restrict__ Wqb,
    u16* __restrict__ Wkb, u16* __restrict__ Wvb,
    float2* __restrict__ tbl)
{
    if (blockIdx.y == 4) {
        int i = blockIdx.x * 256 + threadIdx.x;
        if (i > 449) return;
        float t0 = TAB_T0 + i * TAB_DLT;
        float t1 = t0 + TAB_DLT;
        float y0 = eb2[0], y1 = y0;
        #pragma unroll 8
        for (int n = 0; n < EXPN; ++n) {
            float w1 = ew1[n], b1 = eb1[n], w2 = ew2[n];
            y0 += fmaxf(fmaf(t0, w1, b1), 0.f) * w2;
            y1 += fmaxf(fmaf(t1, w1, b1), 0.f) * w2;
        }
        tbl[i] = make_float2(y0, y1 - y0);
        return;
    }
    const float* s; u16* d; int n;
    switch (blockIdx.y) {
        case 0:  s = X;  d = Xb;  n = (BN * SN) * DN; break;
        case 1:  s = Wq; d = Wqb; n = DN * DN; break;
        case 2:  s = Wk; d = Wkb; n = DN * DN; break;
        default: s = Wv; d = Wvb; n = DN * DN; break;
    }
    int i = (blockIdx.x * 256 + threadIdx.x) * 4;
    if (i < n) {
        float4 v = *(const float4*)&s[i];
        unsigned int lo = (unsigned)f2b(v.x) | ((unsigned)f2b(v.y) << 16);
        unsigned int hi = (unsigned)f2b(v.z) | ((unsigned)f2b(v.w) << 16);
        *(uint2*)&d[i] = make_uint2(lo, hi);
    }
}

// ---------------------------------------------------------------------------
// Kernel 1: fused QKV projection. BM=128 x BN=64, BK=64 (12 K-steps, half the
// barriers of BK=32), 4 waves, global_load_lds staging, XOR swizzle
// byte^=(row&7)<<4 (row stride 128 B), inverse-swizzled global source.
// Q/K stored bf16 [B,NH,S,DH]; V stored TRANSPOSED f16 [B,NH,DH,S].
// ---------------------------------------------------------------------------
__global__ __launch_bounds__(256) void qkv_mfma(
    const u16* __restrict__ Xb,
    const u16* __restrict__ Wqb, const u16* __restrict__ Wkb, const u16* __restrict__ Wvb,
    const float* __restrict__ bq, const float* __restrict__ bk, const float* __restrict__ bv,
    u16* __restrict__ Qb, u16* __restrict__ Kb, u16* __restrict__ Vtr)
{
    __shared__ __align__(16) u16 As[128 * 64];   // 16 KB
    __shared__ __align__(16) u16 Bs[64 * 64];    // 8 KB

    const int tid = threadIdx.x, w = tid >> 6, l = tid & 63;
    const int lr = l & 15, lg = l >> 4;
    const int m0 = blockIdx.y * 128;
    const int nsel = blockIdx.x / 12;
    const int n0l = (blockIdx.x % 12) * 64;
    const u16* W = (nsel == 0) ? Wqb : (nsel == 1) ? Wkb : Wvb;
    const float* bias = (nsel == 0) ? bq : (nsel == 1) ? bk : bv;

    const int wm = w >> 1, wn = w & 1;

    // staging geometry: issue i covers LDS bytes [i*4096, i*4096+4096);
    // row = o>>7, in-row byte = o&127, source col = (inb ^ ((row&7)<<4))/2
    const u16* gA[4];
    int ldsA[4];
    #pragma unroll
    for (int i = 0; i < 4; ++i) {
        int o = i * 4096 + tid * 16;
        int row = o >> 7, inb = o & 127;
        int col = (inb ^ ((row & 7) << 4)) >> 1;
        gA[i] = Xb + (m0 + row) * DN + col;
        ldsA[i] = o;
    }
    const u16* gB[2];
    int ldsB[2];
    #pragma unroll
    for (int i = 0; i < 2; ++i) {
        int o = i * 4096 + tid * 16;
        int row = o >> 7, inb = o & 127;
        int col = (inb ^ ((row & 7) << 4)) >> 1;
        gB[i] = W + (n0l + row) * DN + col;
        ldsB[i] = o;
    }

    // swizzled ds_read byte offsets: frag (row, ks) at bytes ks*64 + lg*16
    int offA[4][2], offB[2][2];
    #pragma unroll
    for (int mi = 0; mi < 4; ++mi) {
        int row = wm * 64 + mi * 16 + lr;
        #pragma unroll
        for (int ks = 0; ks < 2; ++ks)
            offA[mi][ks] = row * 128 + ((ks * 64 + lg * 16) ^ ((row & 7) << 4));
    }
    #pragma unroll
    for (int ni = 0; ni < 2; ++ni) {
        int row = wn * 32 + ni * 16 + lr;
        #pragma unroll
        for (int ks = 0; ks < 2; ++ks)
            offB[ni][ks] = row * 128 + ((ks * 64 + lg * 16) ^ ((row & 7) << 4));
    }

    f32x4 acc[4][2];
    #pragma unroll
    for (int mi = 0; mi < 4; ++mi)
        #pragma unroll
        for (int ni = 0; ni < 2; ++ni) acc[mi][ni] = (f32x4){0.f, 0.f, 0.f, 0.f};

    for (int k0 = 0; k0 < DN; k0 += 64) {
        __syncthreads();
        #pragma unroll
        for (int i = 0; i < 4; ++i) GLD16(gA[i] + k0, (char*)As + ldsA[i]);
        #pragma unroll
        for (int i = 0; i < 2; ++i) GLD16(gB[i] + k0, (char*)Bs + ldsB[i]);
        __syncthreads();

        bf16x8 af[4][2], bff[2][2];
        #pragma unroll
        for (int mi = 0; mi < 4; ++mi)
            #pragma unroll
            for (int ks = 0; ks < 2; ++ks)
                af[mi][ks] = *(const bf16x8*)((const char*)As + offA[mi][ks]);
        #pragma unroll
        for (int ni = 0; ni < 2; ++ni)
            #pragma unroll
            for (int ks = 0; ks < 2; ++ks)
                bff[ni][ks] = *(const bf16x8*)((const char*)Bs + offB[ni][ks]);
        #pragma unroll
        for (int mi = 0; mi < 4; ++mi)
            #pragma unroll
            for (int ni = 0; ni < 2; ++ni) {
                acc[mi][ni] = __builtin_amdgcn_mfma_f32_16x16x32_bf16(af[mi][0], bff[ni][0], acc[mi][ni], 0, 0, 0);
                acc[mi][ni] = __builtin_amdgcn_mfma_f32_16x16x32_bf16(af[mi][1], bff[ni][1], acc[mi][ni], 0, 0, 0);
            }
    }

    if (nsel < 2) {
        u16* out = (nsel == 0) ? Qb : Kb;
        #pragma unroll
        for (int ni = 0; ni < 2; ++ni) {
            int col = n0l + wn * 32 + ni * 16 + lr;
            float bc = bias[col];
            int hh = col >> 6, dh = col & 63;
            #pragma unroll
            for (int mi = 0; mi < 4; ++mi) {
                #pragma unroll
                for (int r = 0; r < 4; ++r) {
                    int m = m0 + wm * 64 + mi * 16 + lg * 4 + r;
                    int bi = m >> 9, srow = m & 511;
                    out[(((bi * NHN + hh) * SN) + srow) * DHN + dh] = f2b(acc[mi][ni][r] + bc);
                }
            }
        }
    } else {
        #pragma unroll
        for (int ni = 0; ni < 2; ++ni) {
            int col = n0l + wn * 32 + ni * 16 + lr;
            float bc = bias[col];
            int hh = col >> 6, dh = col & 63;
            #pragma unroll
            for (int mi = 0; mi < 4; ++mi) {
                int m = m0 + wm * 64 + mi * 16 + lg * 4;
                int bi = m >> 9, srow = m & 511;
                ushort4 pk;
                pk.x = f2h(acc[mi][ni][0] + bc);
                pk.y = f2h(acc[mi][ni][1] + bc);
                pk.z = f2h(acc[mi][ni][2] + bc);
                pk.w = f2h(acc[mi][ni][3] + bc);
                *(ushort4*)&Vtr[((size_t)(bi * NHN + hh) * DHN + dh) * SN + srow] = pk;
            }
        }
    }
}

// ---------------------------------------------------------------------------
// Kernel 2: attention — R16 structure (best known: kh-split PV, pvbuf aliased
// into sb, setprio, 450-entry table, LDS 40448 -> 4 blocks/CU, (512,6)),
// plus myref/mask fold (one fmaf per element).
// ---------------------------------------------------------------------------
__global__ __launch_bounds__(512, 6) void attn_mfma(
    const u16* __restrict__ Qb, const u16* __restrict__ Kb, const u16* __restrict__ Vtr,
    const float* __restrict__ mask, const float2* __restrict__ tbl,
    const float* __restrict__ iw1, const float* __restrict__ ib1,
    const float* __restrict__ iw2, const float* __restrict__ ib2,
    float* __restrict__ out)
{
    __shared__ __align__(16) u16 sb[32 * 512];     // X_up tile; pvbuf aliases head
    __shared__ __align__(16) float2 tab[450];
    __shared__ float ms[SN];
    __shared__ float wI1[INVN], wIb1[INVN], wI2[INVN];
    __shared__ float partw[8][32];
    __shared__ float scale_s[32];
    __shared__ float scal;

    const int tid = threadIdx.x, w = tid >> 6, l = tid & 63;
    const int lr = l & 15, lg = l >> 4, kb8 = lg * 8;
    const int bid = blockIdx.x;
    const int bh = bid >> 4;                       // head 0..47
    const int q0 = (bid & 15) * 32;
    const int b = bh / NHN, h = bh % NHN;
    const u16* Qh = Qb + (size_t)bh * SN * DHN;
    const u16* Kh = Kb + (size_t)bh * SN * DHN;
    const u16* VTh = Vtr + (size_t)bh * DHN * SN;

    if (tid < INVN) { wI1[tid] = iw1[tid]; wIb1[tid] = ib1[tid]; wI2[tid] = iw2[tid]; }
    if (tid == 511) scal = ib2[0];
    if (tid < SN) ms[tid] = mask[b * SN + tid];
    if (tid < 450) tab[tid] = tbl[tid];
    __syncthreads();

    const float ib2v = scal;

    bf16x8 aq00 = *(const bf16x8*)(Qh + (q0 + lr) * DHN + kb8);
    bf16x8 aq01 = *(const bf16x8*)(Qh + (q0 + lr) * DHN + 32 + kb8);
    bf16x8 aq10 = *(const bf16x8*)(Qh + (q0 + 16 + lr) * DHN + kb8);
    bf16x8 aq11 = *(const bf16x8*)(Qh + (q0 + 16 + lr) * DHN + 32 + kb8);

    // refs: score[b,h,0,q0+row] via Q0-replicated A, per m-tile (store ref-1)
    float myref0m1[4], myref1m1[4];
    {
        bf16x8 a00 = *(const bf16x8*)(Qh + kb8);
        bf16x8 a01 = *(const bf16x8*)(Qh + 32 + kb8);
        const u16* kp0 = Kh + (q0 + lr) * DHN + kb8;
        bf16x8 b00 = *(const bf16x8*)(kp0);
        bf16x8 b01 = *(const bf16x8*)(kp0 + 32);
        const u16* kp1 = Kh + (q0 + 16 + lr) * DHN + kb8;
        bf16x8 b10 = *(const bf16x8*)(kp1);
        bf16x8 b11 = *(const bf16x8*)(kp1 + 32);
        f32x4 d0 = {0.f, 0.f, 0.f, 0.f}, d1 = {0.f, 0.f, 0.f, 0.f};
        d0 = __builtin_amdgcn_mfma_f32_16x16x32_bf16(a00, b00, d0, 0, 0, 0);
        d0 = __builtin_amdgcn_mfma_f32_16x16x32_bf16(a01, b01, d0, 0, 0, 0);
        d1 = __builtin_amdgcn_mfma_f32_16x16x32_bf16(a00, b10, d1, 0, 0, 0);
        d1 = __builtin_amdgcn_mfma_f32_16x16x32_bf16(a01, b11, d1, 0, 0, 0);
        float rc0 = d0[0] * 0.125f + ms[q0 + lr] - 1.0f;
        float rc1 = d1[0] * 0.125f + ms[q0 + 16 + lr] - 1.0f;
        #pragma unroll
        for (int r = 0; r < 4; ++r) {
            myref0m1[r] = __shfl(rc0, lg * 4 + r);
            myref1m1[r] = __shfl(rc1, lg * 4 + r);
        }
    }

    // ---- fused QK^T + table lookup over this wave's 64-key strip ----
    char* sbb = (char*)sb;
    float part0[4] = {0.f, 0.f, 0.f, 0.f};
    float part1[4] = {0.f, 0.f, 0.f, 0.f};
    const u16* kpp = Kh + (w * 64 + lr) * DHN + kb8;
    bf16x8 nb0 = *(const bf16x8*)(kpp);
    bf16x8 nb1 = *(const bf16x8*)(kpp + 32);
    #pragma unroll
    for (int i = 0; i < 4; ++i) {
        bf16x8 b0 = nb0, b1 = nb1;
        if (i < 3) {
            const u16* kn = kpp + (i + 1) * 16 * DHN;
            nb0 = *(const bf16x8*)(kn);
            nb1 = *(const bf16x8*)(kn + 32);
        }
        f32x4 d0 = {0.f, 0.f, 0.f, 0.f}, d1 = {0.f, 0.f, 0.f, 0.f};
        __builtin_amdgcn_s_setprio(1);
        d0 = __builtin_amdgcn_mfma_f32_16x16x32_bf16(aq00, b0, d0, 0, 0, 0);
        d0 = __builtin_amdgcn_mfma_f32_16x16x32_bf16(aq01, b1, d0, 0, 0, 0);
        d1 = __builtin_amdgcn_mfma_f32_16x16x32_bf16(aq10, b0, d1, 0, 0, 0);
        d1 = __builtin_amdgcn_mfma_f32_16x16x32_bf16(aq11, b1, d1, 0, 0, 0);
        __builtin_amdgcn_s_setprio(0);
        const int col0 = w * 64 + i * 16;
        const float mv = ms[col0 + lr];
        const int colb = (col0 + lr) * 2;
        float mr0[4], mr1[4];
        #pragma unroll
        for (int r = 0; r < 4; ++r) {
            mr0[r] = mv - myref0m1[r];
            mr1[r] = mv - myref1m1[r];
        }
        #pragma unroll
        for (int r = 0; r < 4; ++r) {
            {   // m-tile 0, row = lg*4+r
                float tp = fminf(fmaf(d0[r], 0.125f, mr0[r]), 3.0f);
                float v = (tp - TAB_T0) * TAB_SCALE;
                int idx = (int)v;
                idx = idx < 0 ? 0 : idx;
                float fr = v - (float)idx;
                float2 p = tab[idx];
                float e = fmaf(fr, p.y, p.x);
                float xu = (tp > -20.0f) ? e : 0.f;
                part0[r] += xu;
                int row = lg * 4 + r;
                *(u16*)(sbb + row * 1024 + (colb ^ ((row & 7) << 4))) = f2h(xu);
            }
            {   // m-tile 1, row = 16 + lg*4+r
                float tp = fminf(fmaf(d1[r], 0.125f, mr1[r]), 3.0f);
                float v = (tp - TAB_T0) * TAB_SCALE;
                int idx = (int)v;
                idx = idx < 0 ? 0 : idx;
                float fr = v - (float)idx;
                float2 p = tab[idx];
                float e = fmaf(fr, p.y, p.x);
                float xu = (tp > -20.0f) ? e : 0.f;
                part1[r] += xu;
                int row = 16 + lg * 4 + r;
                *(u16*)(sbb + row * 1024 + (colb ^ ((row & 7) << 4))) = f2h(xu);
            }
        }
    }
    #pragma unroll
    for (int r = 0; r < 4; ++r) {
        #pragma unroll
        for (int s = 1; s < 16; s <<= 1) {
            part0[r] += __shfl_xor(part0[r], s);
            part1[r] += __shfl_xor(part1[r], s);
        }
    }
    if (lr == 0) {
        #pragma unroll
        for (int r = 0; r < 4; ++r) {
            partw[w][lg * 4 + r] = part0[r];
            partw[w][16 + lg * 4 + r] = part1[r];
        }
    }
    __syncthreads();

    // ---- row scales: wave w handles rows 4w..4w+3 (inv MLP lane-parallel) ----
    #pragma unroll
    for (int rr = 0; rr < 4; ++rr) {
        const int row = w * 4 + rr;
        float pt = 0.f;
        #pragma unroll
        for (int ww = 0; ww < 8; ++ww) pt += partw[ww][row];
        float hu = fmaxf(fmaf(pt, wI1[l], wIb1[l]), 0.f) * wI2[l];
        #pragma unroll
        for (int s = 32; s > 0; s >>= 1) hu += __shfl_xor(hu, s);
        const float pinv = hu + ib2v;
        const float p2 = pt * pinv;
        float hu2 = fmaxf(fmaf(p2, wI1[l], wIb1[l]), 0.f) * wI2[l];
        #pragma unroll
        for (int s = 32; s > 0; s >>= 1) hu2 += __shfl_xor(hu2, s);
        const float pinv2 = hu2 + ib2v;
        if (l == 0) scale_s[row] = pinv * ((p2 > 1.5f) ? pinv2 : 1.0f);
    }

    // ---- PV (f16 MFMA): dh strip ds=(w&3)*16, K-half kh=w>>2, both m-tiles ----
    const int ds = (w & 3) * 16, kh = w >> 2;
    f32x4 acc0 = {0.f, 0.f, 0.f, 0.f}, acc1 = {0.f, 0.f, 0.f, 0.f};
    const u16* vp = VTh + (ds + lr) * SN + kh * 256 + kb8;
    const int swzl = (lr & 7) << 4;
    bf16x8 nv = *(const bf16x8*)(vp);
    #pragma unroll
    for (int k0 = 0; k0 < 256; k0 += 32) {
        bf16x8 bv = nv;
        if (k0 < 224) nv = *(const bf16x8*)(vp + k0 + 32);
        const int kk2 = (kh * 256 + k0 + kb8) * 2;
        bf16x8 a0 = *(const bf16x8*)(sbb + lr * 1024 + (kk2 ^ swzl));
        bf16x8 a1 = *(const bf16x8*)(sbb + (16 + lr) * 1024 + (kk2 ^ swzl));
        __builtin_amdgcn_s_setprio(1);
        acc0 = __builtin_amdgcn_mfma_f32_16x16x32_f16(a0, bv, acc0, 0, 0, 0);
        acc1 = __builtin_amdgcn_mfma_f32_16x16x32_f16(a1, bv, acc1, 0, 0, 0);
        __builtin_amdgcn_s_setprio(0);
    }
    float (*pvbuf)[68] = (float (*)[68])sbb;
    __syncthreads();   // all sb reads complete before aliased writes
    if (kh == 1) {
        #pragma unroll
        for (int r = 0; r < 4; ++r) {
            pvbuf[lg * 4 + r][ds + lr] = acc0[r];
            pvbuf[16 + lg * 4 + r][ds + lr] = acc1[r];
        }
    }
    __syncthreads();
    if (kh == 0) {
        #pragma unroll
        for (int r = 0; r < 4; ++r) {
            const int row0 = lg * 4 + r;
            const int row1 = row0 + 16;
            float v0 = (acc0[r] + pvbuf[row0][ds + lr]) * scale_s[row0];
            float v1 = (acc1[r] + pvbuf[row1][ds + lr]) * scale_s[row1];
            out[(size_t)(b * SN + q0 + row0) * DN + h * DHN + ds + lr] = v0;
            out[(size_t)(b * SN + q0 + row1) * DN + h * DHN + ds + lr] = v1;
        }
    }
}

// ---------------------------------------------------------------------------
extern "C" void kernel_launch(void* const* d_in, const int* in_sizes, int n_in,
                              void* d_out, int out_size, void* d_ws, size_t ws_size,
                              hipStream_t stream) {
    const float* X    = (const float*)d_in[0];
    const float* mask = (const float*)d_in[1];
    const float* Wq   = (const float*)d_in[2];
    const float* bq   = (const float*)d_in[3];
    const float* Wk   = (const float*)d_in[4];
    const float* bk   = (const float*)d_in[5];
    const float* Wv   = (const float*)d_in[6];
    const float* bv   = (const float*)d_in[7];
    const float* ew1  = (const float*)d_in[8];
    const float* eb1  = (const float*)d_in[9];
    const float* ew2  = (const float*)d_in[10];
    const float* eb2  = (const float*)d_in[11];
    const float* iw1  = (const float*)d_in[12];
    const float* ib1  = (const float*)d_in[13];
    const float* iw2  = (const float*)d_in[14];
    const float* ib2  = (const float*)d_in[15];
    float* out = (float*)d_out;

    float2* tbl = (float2*)d_ws;
    u16* Xb  = (u16*)((char*)d_ws + 4608);
    u16* Wqb = Xb + (size_t)(BN * SN) * DN;
    u16* Wkb = Wqb + DN * DN;
    u16* Wvb = Wkb + DN * DN;
    u16* Qb  = Wvb + DN * DN;
    const size_t per = (size_t)BN * NHN * SN * DHN;
    u16* Kb2 = Qb + per;
    u16* Vb2 = Kb2 + per;              // V^T [B,NH,DH,S], f16

    dim3 gc(1536, 5);
    prep<<<gc, 256, 0, stream>>>(X, Wq, Wk, Wv, ew1, eb1, ew2, eb2,
                                 Xb, Wqb, Wkb, Wvb, tbl);

    dim3 g1(36, 16);
    qkv_mfma<<<g1, 256, 0, stream>>>(Xb, Wqb, Wkb, Wvb, bq, bk, bv, Qb, Kb2, Vb2);

    attn_mfma<<<dim3(768), 512, 0, stream>>>(Qb, Kb2, Vb2, mask, tbl,
                                             iw1, ib1, iw2, ib2, out);
}

// Round 18
// 48.999 us; speedup vs baseline: 1.3990x; 1.0740x over previous
//
#include <hip/hip_runtime.h>
#include <math.h>

typedef unsigned short u16;
typedef short bf16x8 __attribute__((ext_vector_type(8)));
typedef float f32x4 __attribute__((ext_vector_type(4)));

#define BN 4
#define SN 512
#define DN 768
#define NHN 12
#define DHN 64
#define EXPN 32
#define INVN 64

#define TAB_T0 -20.5f
#define TAB_DLT (23.5f / 448.0f)
#define TAB_SCALE (448.0f / 23.5f)

__device__ __forceinline__ u16 f2b(float f) {
    union { float f; unsigned int u; } v; v.f = f;
    unsigned int r = v.u + 0x7FFFu + ((v.u >> 16) & 1u);
    return (u16)(r >> 16);
}
__device__ __forceinline__ u16 f2h(float f) {
    union { _Float16 h; u16 u; } v; v.h = (_Float16)f; return v.u;
}

#define GLD16(g, l) __builtin_amdgcn_global_load_lds( \
    (__attribute__((address_space(1))) const void*)(g), \
    (__attribute__((address_space(3))) void*)(l), 16, 0, 0)

// ---------------------------------------------------------------------------
// Kernel 0: f32->bf16 conversion of X/Wq/Wk/Wv + PWL table (blockIdx.y==4).
// ---------------------------------------------------------------------------
__global__ __launch_bounds__(256) void prep(
    const float* __restrict__ X, const float* __restrict__ Wq,
    const float* __restrict__ Wk, const float* __restrict__ Wv,
    const float* __restrict__ ew1, const float* __restrict__ eb1,
    const float* __restrict__ ew2, const float* __restrict__ eb2,
    u16* __restrict__ Xb, u16* __restrict__ Wqb,
    u16* __restrict__ Wkb, u16* __restrict__ Wvb,
    float2* __restrict__ tbl)
{
    if (blockIdx.y == 4) {
        int i = blockIdx.x * 256 + threadIdx.x;
        if (i > 449) return;
        float t0 = TAB_T0 + i * TAB_DLT;
        float t1 = t0 + TAB_DLT;
        float y0 = eb2[0], y1 = y0;
        #pragma unroll 8
        for (int n = 0; n < EXPN; ++n) {
            float w1 = ew1[n], b1 = eb1[n], w2 = ew2[n];
            y0 += fmaxf(fmaf(t0, w1, b1), 0.f) * w2;
            y1 += fmaxf(fmaf(t1, w1, b1), 0.f) * w2;
        }
        tbl[i] = make_float2(y0, y1 - y0);
        return;
    }
    const float* s; u16* d; int n;
    switch (blockIdx.y) {
        case 0:  s = X;  d = Xb;  n = (BN * SN) * DN; break;
        case 1:  s = Wq; d = Wqb; n = DN * DN; break;
        case 2:  s = Wk; d = Wkb; n = DN * DN; break;
        default: s = Wv; d = Wvb; n = DN * DN; break;
    }
    int i = (blockIdx.x * 256 + threadIdx.x) * 4;
    if (i < n) {
        float4 v = *(const float4*)&s[i];
        unsigned int lo = (unsigned)f2b(v.x) | ((unsigned)f2b(v.y) << 16);
        unsigned int hi = (unsigned)f2b(v.z) | ((unsigned)f2b(v.w) << 16);
        *(uint2*)&d[i] = make_uint2(lo, hi);
    }
}

// ---------------------------------------------------------------------------
// Kernel 1: fused QKV projection. BM=128 x BN=64, BK=128 (6 K-steps, half the
// barriers of BK=64), 4 waves, global_load_lds staging, XOR swizzle
// byte^=(row&7)<<4 (row stride 256 B), inverse-swizzled global source.
// Per-ks fragment loading bounds live VGPRs. LDS 48 KB -> 3 blocks/CU
// (>= 2.25 grid average, occupancy unchanged).
// ---------------------------------------------------------------------------
__global__ __launch_bounds__(256) void qkv_mfma(
    const u16* __restrict__ Xb,
    const u16* __restrict__ Wqb, const u16* __restrict__ Wkb, const u16* __restrict__ Wvb,
    const float* __restrict__ bq, const float* __restrict__ bk, const float* __restrict__ bv,
    u16* __restrict__ Qb, u16* __restrict__ Kb, u16* __restrict__ Vtr)
{
    __shared__ __align__(16) u16 As[128 * 128];  // 32 KB, row stride 256 B
    __shared__ __align__(16) u16 Bs[64 * 128];   // 16 KB

    const int tid = threadIdx.x, w = tid >> 6, l = tid & 63;
    const int lr = l & 15, lg = l >> 4;
    const int m0 = blockIdx.y * 128;
    const int nsel = blockIdx.x / 12;
    const int n0l = (blockIdx.x % 12) * 64;
    const u16* W = (nsel == 0) ? Wqb : (nsel == 1) ? Wkb : Wvb;
    const float* bias = (nsel == 0) ? bq : (nsel == 1) ? bk : bv;

    const int wm = w >> 1, wn = w & 1;

    // staging: row = o>>8, in-row byte = o&255, src col = (inb ^ ((row&7)<<4))/2
    const u16* gA[8];
    int ldsA[8];
    #pragma unroll
    for (int i = 0; i < 8; ++i) {
        int o = i * 4096 + tid * 16;
        int row = o >> 8, inb = o & 255;
        int col = (inb ^ ((row & 7) << 4)) >> 1;
        gA[i] = Xb + (m0 + row) * DN + col;
        ldsA[i] = o;
    }
    const u16* gB[4];
    int ldsB[4];
    #pragma unroll
    for (int i = 0; i < 4; ++i) {
        int o = i * 4096 + tid * 16;
        int row = o >> 8, inb = o & 255;
        int col = (inb ^ ((row & 7) << 4)) >> 1;
        gB[i] = W + (n0l + row) * DN + col;
        ldsB[i] = o;
    }

    // swizzled ds_read byte offsets: frag (row, ks) at bytes ks*64 + lg*16
    int offA[4][4], offB[2][4];
    #pragma unroll
    for (int mi = 0; mi < 4; ++mi) {
        int row = wm * 64 + mi * 16 + lr;
        #pragma unroll
        for (int ks = 0; ks < 4; ++ks)
            offA[mi][ks] = row * 256 + ((ks * 64 + lg * 16) ^ ((row & 7) << 4));
    }
    #pragma unroll
    for (int ni = 0; ni < 2; ++ni) {
        int row = wn * 32 + ni * 16 + lr;
        #pragma unroll
        for (int ks = 0; ks < 4; ++ks)
            offB[ni][ks] = row * 256 + ((ks * 64 + lg * 16) ^ ((row & 7) << 4));
    }

    f32x4 acc[4][2];
    #pragma unroll
    for (int mi = 0; mi < 4; ++mi)
        #pragma unroll
        for (int ni = 0; ni < 2; ++ni) acc[mi][ni] = (f32x4){0.f, 0.f, 0.f, 0.f};

    for (int k0 = 0; k0 < DN; k0 += 128) {
        __syncthreads();
        #pragma unroll
        for (int i = 0; i < 8; ++i) GLD16(gA[i] + k0, (char*)As + ldsA[i]);
        #pragma unroll
        for (int i = 0; i < 4; ++i) GLD16(gB[i] + k0, (char*)Bs + ldsB[i]);
        __syncthreads();

        #pragma unroll
        for (int ks = 0; ks < 4; ++ks) {
            bf16x8 af[4], bff[2];
            #pragma unroll
            for (int mi = 0; mi < 4; ++mi)
                af[mi] = *(const bf16x8*)((const char*)As + offA[mi][ks]);
            #pragma unroll
            for (int ni = 0; ni < 2; ++ni)
                bff[ni] = *(const bf16x8*)((const char*)Bs + offB[ni][ks]);
            #pragma unroll
            for (int mi = 0; mi < 4; ++mi)
                #pragma unroll
                for (int ni = 0; ni < 2; ++ni)
                    acc[mi][ni] = __builtin_amdgcn_mfma_f32_16x16x32_bf16(af[mi], bff[ni], acc[mi][ni], 0, 0, 0);
        }
    }

    if (nsel < 2) {
        u16* out = (nsel == 0) ? Qb : Kb;
        #pragma unroll
        for (int ni = 0; ni < 2; ++ni) {
            int col = n0l + wn * 32 + ni * 16 + lr;
            float bc = bias[col];
            int hh = col >> 6, dh = col & 63;
            #pragma unroll
            for (int mi = 0; mi < 4; ++mi) {
                #pragma unroll
                for (int r = 0; r < 4; ++r) {
                    int m = m0 + wm * 64 + mi * 16 + lg * 4 + r;
                    int bi = m >> 9, srow = m & 511;
                    out[(((bi * NHN + hh) * SN) + srow) * DHN + dh] = f2b(acc[mi][ni][r] + bc);
                }
            }
        }
    } else {
        #pragma unroll
        for (int ni = 0; ni < 2; ++ni) {
            int col = n0l + wn * 32 + ni * 16 + lr;
            float bc = bias[col];
            int hh = col >> 6, dh = col & 63;
            #pragma unroll
            for (int mi = 0; mi < 4; ++mi) {
                int m = m0 + wm * 64 + mi * 16 + lg * 4;
                int bi = m >> 9, srow = m & 511;
                ushort4 pk;
                pk.x = f2h(acc[mi][ni][0] + bc);
                pk.y = f2h(acc[mi][ni][1] + bc);
                pk.z = f2h(acc[mi][ni][2] + bc);
                pk.w = f2h(acc[mi][ni][3] + bc);
                *(ushort4*)&Vtr[((size_t)(bi * NHN + hh) * DHN + dh) * SN + srow] = pk;
            }
        }
    }
}

// ---------------------------------------------------------------------------
// Kernel 2: attention — R17 structure with 2-deep prefetch on the QK K-loop
// and the PV V-loop (VGPR ~56, under the (512,6) cap of 85 — no spill).
// ---------------------------------------------------------------------------
__global__ __launch_bounds__(512, 6) void attn_mfma(
    const u16* __restrict__ Qb, const u16* __restrict__ Kb, const u16* __restrict__ Vtr,
    const float* __restrict__ mask, const float2* __restrict__ tbl,
    const float* __restrict__ iw1, const float* __restrict__ ib1,
    const float* __restrict__ iw2, const float* __restrict__ ib2,
    float* __restrict__ out)
{
    __shared__ __align__(16) u16 sb[32 * 512];     // X_up tile; pvbuf aliases head
    __shared__ __align__(16) float2 tab[450];
    __shared__ float ms[SN];
    __shared__ float wI1[INVN], wIb1[INVN], wI2[INVN];
    __shared__ float partw[8][32];
    __shared__ float scale_s[32];
    __shared__ float scal;

    const int tid = threadIdx.x, w = tid >> 6, l = tid & 63;
    const int lr = l & 15, lg = l >> 4, kb8 = lg * 8;
    const int bid = blockIdx.x;
    const int bh = bid >> 4;                       // head 0..47
    const int q0 = (bid & 15) * 32;
    const int b = bh / NHN, h = bh % NHN;
    const u16* Qh = Qb + (size_t)bh * SN * DHN;
    const u16* Kh = Kb + (size_t)bh * SN * DHN;
    const u16* VTh = Vtr + (size_t)bh * DHN * SN;

    if (tid < INVN) { wI1[tid] = iw1[tid]; wIb1[tid] = ib1[tid]; wI2[tid] = iw2[tid]; }
    if (tid == 511) scal = ib2[0];
    if (tid < SN) ms[tid] = mask[b * SN + tid];
    if (tid < 450) tab[tid] = tbl[tid];
    __syncthreads();

    const float ib2v = scal;

    bf16x8 aq00 = *(const bf16x8*)(Qh + (q0 + lr) * DHN + kb8);
    bf16x8 aq01 = *(const bf16x8*)(Qh + (q0 + lr) * DHN + 32 + kb8);
    bf16x8 aq10 = *(const bf16x8*)(Qh + (q0 + 16 + lr) * DHN + kb8);
    bf16x8 aq11 = *(const bf16x8*)(Qh + (q0 + 16 + lr) * DHN + 32 + kb8);

    // refs: score[b,h,0,q0+row] via Q0-replicated A, per m-tile (store ref-1)
    float myref0m1[4], myref1m1[4];
    {
        bf16x8 a00 = *(const bf16x8*)(Qh + kb8);
        bf16x8 a01 = *(const bf16x8*)(Qh + 32 + kb8);
        const u16* kp0 = Kh + (q0 + lr) * DHN + kb8;
        bf16x8 b00 = *(const bf16x8*)(kp0);
        bf16x8 b01 = *(const bf16x8*)(kp0 + 32);
        const u16* kp1 = Kh + (q0 + 16 + lr) * DHN + kb8;
        bf16x8 b10 = *(const bf16x8*)(kp1);
        bf16x8 b11 = *(const bf16x8*)(kp1 + 32);
        f32x4 d0 = {0.f, 0.f, 0.f, 0.f}, d1 = {0.f, 0.f, 0.f, 0.f};
        d0 = __builtin_amdgcn_mfma_f32_16x16x32_bf16(a00, b00, d0, 0, 0, 0);
        d0 = __builtin_amdgcn_mfma_f32_16x16x32_bf16(a01, b01, d0, 0, 0, 0);
        d1 = __builtin_amdgcn_mfma_f32_16x16x32_bf16(a00, b10, d1, 0, 0, 0);
        d1 = __builtin_amdgcn_mfma_f32_16x16x32_bf16(a01, b11, d1, 0, 0, 0);
        float rc0 = d0[0] * 0.125f + ms[q0 + lr] - 1.0f;
        float rc1 = d1[0] * 0.125f + ms[q0 + 16 + lr] - 1.0f;
        #pragma unroll
        for (int r = 0; r < 4; ++r) {
            myref0m1[r] = __shfl(rc0, lg * 4 + r);
            myref1m1[r] = __shfl(rc1, lg * 4 + r);
        }
    }

    // ---- fused QK^T + table lookup, 2-deep K prefetch ----
    char* sbb = (char*)sb;
    float part0[4] = {0.f, 0.f, 0.f, 0.f};
    float part1[4] = {0.f, 0.f, 0.f, 0.f};
    const u16* kpp = Kh + (w * 64 + lr) * DHN + kb8;
    bf16x8 p00 = *(const bf16x8*)(kpp);
    bf16x8 p01 = *(const bf16x8*)(kpp + 32);
    bf16x8 p10 = *(const bf16x8*)(kpp + 16 * DHN);
    bf16x8 p11 = *(const bf16x8*)(kpp + 16 * DHN + 32);
    #pragma unroll
    for (int i = 0; i < 4; ++i) {
        bf16x8 b0 = p00, b1 = p01;
        p00 = p10; p01 = p11;
        if (i < 2) {
            const u16* kn = kpp + (i + 2) * 16 * DHN;
            p10 = *(const bf16x8*)(kn);
            p11 = *(const bf16x8*)(kn + 32);
        }
        f32x4 d0 = {0.f, 0.f, 0.f, 0.f}, d1 = {0.f, 0.f, 0.f, 0.f};
        __builtin_amdgcn_s_setprio(1);
        d0 = __builtin_amdgcn_mfma_f32_16x16x32_bf16(aq00, b0, d0, 0, 0, 0);
        d0 = __builtin_amdgcn_mfma_f32_16x16x32_bf16(aq01, b1, d0, 0, 0, 0);
        d1 = __builtin_amdgcn_mfma_f32_16x16x32_bf16(aq10, b0, d1, 0, 0, 0);
        d1 = __builtin_amdgcn_mfma_f32_16x16x32_bf16(aq11, b1, d1, 0, 0, 0);
        __builtin_amdgcn_s_setprio(0);
        const int col0 = w * 64 + i * 16;
        const float mv = ms[col0 + lr];
        const int colb = (col0 + lr) * 2;
        float mr0[4], mr1[4];
        #pragma unroll
        for (int r = 0; r < 4; ++r) {
            mr0[r] = mv - myref0m1[r];
            mr1[r] = mv - myref1m1[r];
        }
        #pragma unroll
        for (int r = 0; r < 4; ++r) {
            {   // m-tile 0, row = lg*4+r
                float tp = fminf(fmaf(d0[r], 0.125f, mr0[r]), 3.0f);
                float v = (tp - TAB_T0) * TAB_SCALE;
                int idx = (int)v;
                idx = idx < 0 ? 0 : idx;
                float fr = v - (float)idx;
                float2 p = tab[idx];
                float e = fmaf(fr, p.y, p.x);
                float xu = (tp > -20.0f) ? e : 0.f;
                part0[r] += xu;
                int row = lg * 4 + r;
                *(u16*)(sbb + row * 1024 + (colb ^ ((row & 7) << 4))) = f2h(xu);
            }
            {   // m-tile 1, row = 16 + lg*4+r
                float tp = fminf(fmaf(d1[r], 0.125f, mr1[r]), 3.0f);
                float v = (tp - TAB_T0) * TAB_SCALE;
                int idx = (int)v;
                idx = idx < 0 ? 0 : idx;
                float fr = v - (float)idx;
                float2 p = tab[idx];
                float e = fmaf(fr, p.y, p.x);
                float xu = (tp > -20.0f) ? e : 0.f;
                part1[r] += xu;
                int row = 16 + lg * 4 + r;
                *(u16*)(sbb + row * 1024 + (colb ^ ((row & 7) << 4))) = f2h(xu);
            }
        }
    }
    #pragma unroll
    for (int r = 0; r < 4; ++r) {
        #pragma unroll
        for (int s = 1; s < 16; s <<= 1) {
            part0[r] += __shfl_xor(part0[r], s);
            part1[r] += __shfl_xor(part1[r], s);
        }
    }
    if (lr == 0) {
        #pragma unroll
        for (int r = 0; r < 4; ++r) {
            partw[w][lg * 4 + r] = part0[r];
            partw[w][16 + lg * 4 + r] = part1[r];
        }
    }
    __syncthreads();

    // ---- row scales: wave w handles rows 4w..4w+3 (inv MLP lane-parallel) ----
    #pragma unroll
    for (int rr = 0; rr < 4; ++rr) {
        const int row = w * 4 + rr;
        float pt = 0.f;
        #pragma unroll
        for (int ww = 0; ww < 8; ++ww) pt += partw[ww][row];
        float hu = fmaxf(fmaf(pt, wI1[l], wIb1[l]), 0.f) * wI2[l];
        #pragma unroll
        for (int s = 32; s > 0; s >>= 1) hu += __shfl_xor(hu, s);
        const float pinv = hu + ib2v;
        const float p2 = pt * pinv;
        float hu2 = fmaxf(fmaf(p2, wI1[l], wIb1[l]), 0.f) * wI2[l];
        #pragma unroll
        for (int s = 32; s > 0; s >>= 1) hu2 += __shfl_xor(hu2, s);
        const float pinv2 = hu2 + ib2v;
        if (l == 0) scale_s[row] = pinv * ((p2 > 1.5f) ? pinv2 : 1.0f);
    }

    // ---- PV (f16 MFMA): dh strip ds=(w&3)*16, K-half kh=w>>2, both m-tiles,
    //      2-deep V prefetch ----
    const int ds = (w & 3) * 16, kh = w >> 2;
    f32x4 acc0 = {0.f, 0.f, 0.f, 0.f}, acc1 = {0.f, 0.f, 0.f, 0.f};
    const u16* vp = VTh + (ds + lr) * SN + kh * 256 + kb8;
    const int swzl = (lr & 7) << 4;
    bf16x8 nv0 = *(const bf16x8*)(vp);
    bf16x8 nv1 = *(const bf16x8*)(vp + 32);
    #pragma unroll
    for (int k0 = 0; k0 < 256; k0 += 32) {
        bf16x8 bv = nv0;
        nv0 = nv1;
        if (k0 < 192) nv1 = *(const bf16x8*)(vp + k0 + 64);
        const int kk2 = (kh * 256 + k0 + kb8) * 2;
        bf16x8 a0 = *(const bf16x8*)(sbb + lr * 1024 + (kk2 ^ swzl));
        bf16x8 a1 = *(const bf16x8*)(sbb + (16 + lr) * 1024 + (kk2 ^ swzl));
        __builtin_amdgcn_s_setprio(1);
        acc0 = __builtin_amdgcn_mfma_f32_16x16x32_f16(a0, bv, acc0, 0, 0, 0);
        acc1 = __builtin_amdgcn_mfma_f32_16x16x32_f16(a1, bv, acc1, 0, 0, 0);
        __builtin_amdgcn_s_setprio(0);
    }
    float (*pvbuf)[68] = (float (*)[68])sbb;
    __syncthreads();   // all sb reads complete before aliased writes
    if (kh == 1) {
        #pragma unroll
        for (int r = 0; r < 4; ++r) {
            pvbuf[lg * 4 + r][ds + lr] = acc0[r];
            pvbuf[16 + lg * 4 + r][ds + lr] = acc1[r];
        }
    }
    __syncthreads();
    if (kh == 0) {
        #pragma unroll
        for (int r = 0; r < 4; ++r) {
            const int row0 = lg * 4 + r;
            const int row1 = row0 + 16;
            float v0 = (acc0[r] + pvbuf[row0][ds + lr]) * scale_s[row0];
            float v1 = (acc1[r] + pvbuf[row1][ds + lr]) * scale_s[row1];
            out[(size_t)(b * SN + q0 + row0) * DN + h * DHN + ds + lr] = v0;
            out[(size_t)(b * SN + q0 + row1) * DN + h * DHN + ds + lr] = v1;
        }
    }
}

// ---------------------------------------------------------------------------
extern "C" void kernel_launch(void* const* d_in, const int* in_sizes, int n_in,
                              void* d_out, int out_size, void* d_ws, size_t ws_size,
                              hipStream_t stream) {
    const float* X    = (const float*)d_in[0];
    const float* mask = (const float*)d_in[1];
    const float* Wq   = (const float*)d_in[2];
    const float* bq   = (const float*)d_in[3];
    const float* Wk   = (const float*)d_in[4];
    const float* bk   = (const float*)d_in[5];
    const float* Wv   = (const float*)d_in[6];
    const float* bv   = (const float*)d_in[7];
    const float* ew1  = (const float*)d_in[8];
    const float* eb1  = (const float*)d_in[9];
    const float* ew2  = (const float*)d_in[10];
    const float* eb2  = (const float*)d_in[11];
    const float* iw1  = (const float*)d_in[12];
    const float* ib1  = (const float*)d_in[13];
    const float* iw2  = (const float*)d_in[14];
    const float* ib2  = (const float*)d_in[15];
    float* out = (float*)d_out;

    float2* tbl = (float2*)d_ws;
    u16* Xb  = (u16*)((char*)d_ws + 4608);
    u16* Wqb = Xb + (size_t)(BN * SN) * DN;
    u16* Wkb = Wqb + DN * DN;
    u16* Wvb = Wkb + DN * DN;
    u16* Qb  = Wvb + DN * DN;
    const size_t per = (size_t)BN * NHN * SN * DHN;
    u16* Kb2 = Qb + per;
    u16* Vb2 = Kb2 + per;              // V^T [B,NH,DH,S], f16

    dim3 gc(1536, 5);
    prep<<<gc, 256, 0, stream>>>(X, Wq, Wk, Wv, ew1, eb1, ew2, eb2,
                                 Xb, Wqb, Wkb, Wvb, tbl);

    dim3 g1(36, 16);
    qkv_mfma<<<g1, 256, 0, stream>>>(Xb, Wqb, Wkb, Wvb, bq, bk, bv, Qb, Kb2, Vb2);

    attn_mfma<<<dim3(768), 512, 0, stream>>>(Qb, Kb2, Vb2, mask, tbl,
                                             iw1, ib1, iw2, ib2, out);
}